// Round 2
// baseline (9535.725 us; speedup 1.0000x reference)
//
#include <hip/hip_runtime.h>
#include <cmath>

#define BH_ 32768ull  // 64*512 floats per timestep of h

__device__ __forceinline__ float sigm(float x) { return 1.0f / (1.0f + __expf(-x)); }

// ---------------- tiled transpose [2048,512] -> [512,2048] ----------------
__global__ __launch_bounds__(256) void transpose_whh(const float* __restrict__ in,
                                                     float* __restrict__ outT) {
  __shared__ float tile[32][33];
  int tx = threadIdx.x & 31, ty = threadIdx.x >> 5;
  int k0 = blockIdx.x * 32;  // 16 tiles over K=512
  int j0 = blockIdx.y * 32;  // 64 tiles over 4H=2048
#pragma unroll
  for (int i = 0; i < 32; i += 8)
    tile[ty + i][tx] = in[(size_t)(j0 + ty + i) * 512 + k0 + tx];
  __syncthreads();
#pragma unroll
  for (int i = 0; i < 32; i += 8)
    outT[(size_t)(k0 + ty + i) * 2048 + j0 + tx] = tile[tx][ty + i];
}

// ---- GEMM: C[r,n] = sum_k Arow(r+m_off)[k] * W[n,k] (+bias1[n]+bias2[n]) ----
// A rows: xmode==1 -> global row g=(t*64+b) maps to x + (b*256+t)*256 ; else A + g*K
// C written at LOCAL rows (r). 128x128 tile, 256 threads, 8x8 micro-tile, K mult of 16.
__global__ __launch_bounds__(256) void gemm_fp32(const float* __restrict__ A,
                                                 const float* __restrict__ W,
                                                 const float* __restrict__ bias1,
                                                 const float* __restrict__ bias2,
                                                 float* __restrict__ C, int N, int K,
                                                 int xmode, int m_off) {
  __shared__ float As[16 * 132];
  __shared__ float Ws[16 * 132];
  int tid = threadIdx.x;
  int n0 = blockIdx.x * 128, m0 = blockIdx.y * 128;
  int row = tid >> 1;
  int kbase = (tid & 1) * 8;
  const float* ap;
  {
    int g = m0 + row + m_off;
    ap = xmode ? (A + (size_t)((g & 63) * 256 + (g >> 6)) * 256) : (A + (size_t)g * K);
  }
  const float* wp = W + (size_t)(n0 + row) * K;
  int ty = tid >> 4, tx = tid & 15;
  float acc[8][8];
#pragma unroll
  for (int i = 0; i < 8; ++i)
#pragma unroll
    for (int j = 0; j < 8; ++j) acc[i][j] = 0.f;

  for (int kt = 0; kt < K; kt += 16) {
    float4 va0 = *(const float4*)(ap + kt + kbase);
    float4 va1 = *(const float4*)(ap + kt + kbase + 4);
    float4 vw0 = *(const float4*)(wp + kt + kbase);
    float4 vw1 = *(const float4*)(wp + kt + kbase + 4);
    __syncthreads();  // previous compute done before overwriting tiles
    As[(kbase + 0) * 132 + row] = va0.x;
    As[(kbase + 1) * 132 + row] = va0.y;
    As[(kbase + 2) * 132 + row] = va0.z;
    As[(kbase + 3) * 132 + row] = va0.w;
    As[(kbase + 4) * 132 + row] = va1.x;
    As[(kbase + 5) * 132 + row] = va1.y;
    As[(kbase + 6) * 132 + row] = va1.z;
    As[(kbase + 7) * 132 + row] = va1.w;
    Ws[(kbase + 0) * 132 + row] = vw0.x;
    Ws[(kbase + 1) * 132 + row] = vw0.y;
    Ws[(kbase + 2) * 132 + row] = vw0.z;
    Ws[(kbase + 3) * 132 + row] = vw0.w;
    Ws[(kbase + 4) * 132 + row] = vw1.x;
    Ws[(kbase + 5) * 132 + row] = vw1.y;
    Ws[(kbase + 6) * 132 + row] = vw1.z;
    Ws[(kbase + 7) * 132 + row] = vw1.w;
    __syncthreads();
#pragma unroll
    for (int kk = 0; kk < 16; ++kk) {
      float4 a0 = *(const float4*)&As[kk * 132 + ty * 8];
      float4 a1 = *(const float4*)&As[kk * 132 + ty * 8 + 4];
      float4 w0 = *(const float4*)&Ws[kk * 132 + tx * 8];
      float4 w1 = *(const float4*)&Ws[kk * 132 + tx * 8 + 4];
      float av[8] = {a0.x, a0.y, a0.z, a0.w, a1.x, a1.y, a1.z, a1.w};
      float wv[8] = {w0.x, w0.y, w0.z, w0.w, w1.x, w1.y, w1.z, w1.w};
#pragma unroll
      for (int i = 0; i < 8; ++i)
#pragma unroll
        for (int j = 0; j < 8; ++j) acc[i][j] = fmaf(av[i], wv[j], acc[i][j]);
    }
  }
  float bsum[8];
#pragma unroll
  for (int j = 0; j < 8; ++j)
    bsum[j] = bias1 ? (bias1[n0 + tx * 8 + j] + bias2[n0 + tx * 8 + j]) : 0.f;
#pragma unroll
  for (int i = 0; i < 8; ++i) {
    float* cp = C + (size_t)(m0 + ty * 8 + i) * N + n0 + tx * 8;
    float4 o0 = make_float4(acc[i][0] + bsum[0], acc[i][1] + bsum[1], acc[i][2] + bsum[2],
                            acc[i][3] + bsum[3]);
    float4 o1 = make_float4(acc[i][4] + bsum[4], acc[i][5] + bsum[5], acc[i][6] + bsum[6],
                            acc[i][7] + bsum[7]);
    *(float4*)cp = o0;
    *(float4*)(cp + 4) = o1;
  }
}

// ---- one LSTM step: gates = h_prev @ Whh.T (+xp, biases prefolded), cell update ----
// WT is Whh transposed: [512][2048]. Grid 256 blocks (8 b-groups x 32 n-groups), 256 thr.
__global__ __launch_bounds__(256) void lstm_step(const float* __restrict__ h_prev,
                                                 const float* __restrict__ c_in,
                                                 float* __restrict__ c_out,
                                                 const float* __restrict__ xp,
                                                 const float* __restrict__ WT,
                                                 float* __restrict__ h_out, int store_c) {
  __shared__ float h_s[8 * 516];
  __shared__ float part[256 * 8];
  int tid = threadIdx.x;
  int bg = blockIdx.x & 7;
  int ng = blockIdx.x >> 3;
  const float4* hsrc = (const float4*)(h_prev + (size_t)bg * 8 * 512);
#pragma unroll
  for (int j = 0; j < 4; ++j) {
    int idx = tid + 256 * j;  // float4 index over 8x512
    float4 v = hsrc[idx];
    int r = idx >> 7, c4 = idx & 127;
    *(float4*)&h_s[r * 516 + c4 * 4] = v;
  }
  __syncthreads();
  int kq = tid >> 6, lane = tid & 63;
  int bp = lane >> 4, nl = lane & 15;
  int n = ng * 16 + nl;
  int k0 = kq * 128;
  const float* hA = &h_s[(bp * 2) * 516 + k0];
  const float* hB = &h_s[(bp * 2 + 1) * 516 + k0];
  const float* wbase = WT + (size_t)k0 * 2048 + n;
  float a00 = 0.f, a01 = 0.f, a02 = 0.f, a03 = 0.f;
  float a10 = 0.f, a11 = 0.f, a12 = 0.f, a13 = 0.f;
#pragma unroll 4
  for (int k = 0; k < 128; ++k) {
    const float* wk = wbase + (size_t)k * 2048;
    float wi = wk[0];
    float wf = wk[512];
    float wg = wk[1024];
    float wo = wk[1536];
    float ha = hA[k], hb = hB[k];
    a00 = fmaf(wi, ha, a00);
    a01 = fmaf(wf, ha, a01);
    a02 = fmaf(wg, ha, a02);
    a03 = fmaf(wo, ha, a03);
    a10 = fmaf(wi, hb, a10);
    a11 = fmaf(wf, hb, a11);
    a12 = fmaf(wg, hb, a12);
    a13 = fmaf(wo, hb, a13);
  }
  float* pr = &part[tid * 8];
  pr[0] = a00; pr[1] = a01; pr[2] = a02; pr[3] = a03;
  pr[4] = a10; pr[5] = a11; pr[6] = a12; pr[7] = a13;
  __syncthreads();
  if (tid < 64) {
    float s[8];
#pragma unroll
    for (int j = 0; j < 8; ++j)
      s[j] = part[tid * 8 + j] + part[(tid + 64) * 8 + j] + part[(tid + 128) * 8 + j] +
             part[(tid + 192) * 8 + j];
    int bp2 = tid >> 4, nl2 = tid & 15;
    int n2 = ng * 16 + nl2;
#pragma unroll
    for (int bi = 0; bi < 2; ++bi) {
      int b = bg * 8 + bp2 * 2 + bi;
      const float* xr = xp + (size_t)b * 2048;
      float pi = s[bi * 4 + 0] + xr[n2];
      float pf = s[bi * 4 + 1] + xr[512 + n2];
      float pg = s[bi * 4 + 2] + xr[1024 + n2];
      float po = s[bi * 4 + 3] + xr[1536 + n2];
      float ig = sigm(pi), fg = sigm(pf), gg = tanhf(pg), og = sigm(po);
      float c = c_in[(size_t)b * 512 + n2];
      float cn = fmaf(fg, c, ig * gg);
      float hn = og * tanhf(cn);
      h_out[(size_t)b * 512 + n2] = hn;
      if (store_c) c_out[(size_t)b * 512 + n2] = cn;
    }
  }
}

// ---- scorer: out[b,t,s] = sum_w vt[w]*tanh(e1[s,b,w] + H2[t,b,w]) ----
// grid (32 s-tiles of 8, 64 b), 128 threads; loops all 16 t-tiles of 16 internally.
__global__ __launch_bounds__(128) void scorer(const float* __restrict__ E1,
                                              const float* __restrict__ H2,
                                              const float* __restrict__ vt,
                                              float* __restrict__ out) {
  __shared__ float e1s[8 * 516];
  __shared__ float h2s[16 * 516];
  int tid = threadIdx.x;
  int sx = blockIdx.x;
  int b = blockIdx.y;
#pragma unroll
  for (int j = 0; j < 8; ++j) {
    int idx = tid + 128 * j;
    int r = idx >> 7, c4 = idx & 127;
    float4 v = *(const float4*)(E1 + ((size_t)(sx * 8 + r) * 64 + b) * 512 + c4 * 4);
    *(float4*)&e1s[r * 516 + c4 * 4] = v;
  }
  int tl = tid >> 3, sl = tid & 7;
  for (int tt = 0; tt < 16; ++tt) {
    __syncthreads();  // protect tiles from previous iteration's readers
#pragma unroll
    for (int j = 0; j < 16; ++j) {
      int idx = tid + 128 * j;
      int r = idx >> 7, c4 = idx & 127;
      float4 v = *(const float4*)(H2 + ((size_t)(tt * 16 + r) * 64 + b) * 512 + c4 * 4);
      *(float4*)&h2s[r * 516 + c4 * 4] = v;
    }
    __syncthreads();
    float acc = 0.f;
    const float* ep = &e1s[sl * 516];
    const float* hp = &h2s[tl * 516];
#pragma unroll 8
    for (int w4 = 0; w4 < 128; ++w4) {
      float4 a = *(const float4*)(ep + w4 * 4);
      float4 h = *(const float4*)(hp + w4 * 4);
      float4 vv = *(const float4*)(vt + w4 * 4);
      float x0 = a.x + h.x, x1 = a.y + h.y, x2 = a.z + h.z, x3 = a.w + h.w;
      // tanh(x) = 1 - 2/(exp(2x)+1); saturates correctly at +/-inf (rcp(inf)=0)
      float t0 = fmaf(-2.f, __builtin_amdgcn_rcpf(__expf(x0 + x0) + 1.f), 1.f);
      float t1 = fmaf(-2.f, __builtin_amdgcn_rcpf(__expf(x1 + x1) + 1.f), 1.f);
      float t2 = fmaf(-2.f, __builtin_amdgcn_rcpf(__expf(x2 + x2) + 1.f), 1.f);
      float t3 = fmaf(-2.f, __builtin_amdgcn_rcpf(__expf(x3 + x3) + 1.f), 1.f);
      acc = fmaf(t0, vv.x, acc);
      acc = fmaf(t1, vv.y, acc);
      acc = fmaf(t2, vv.z, acc);
      acc = fmaf(t3, vv.w, acc);
    }
    out[((size_t)b * 256 + tt * 16 + tl) * 256 + sx * 8 + sl] = acc;
  }
}

// ---- in-place log_softmax over last dim (rows of 256) ----
__global__ __launch_bounds__(256) void logsoftmax_kernel(float* __restrict__ out) {
  __shared__ float red[256];
  int tid = threadIdx.x;
  float* row = out + (size_t)blockIdx.x * 256;
  float v = row[tid];
  red[tid] = v;
  __syncthreads();
  for (int off = 128; off > 0; off >>= 1) {
    if (tid < off) red[tid] = fmaxf(red[tid], red[tid + off]);
    __syncthreads();
  }
  float mx = red[0];
  __syncthreads();
  red[tid] = __expf(v - mx);
  __syncthreads();
  for (int off = 128; off > 0; off >>= 1) {
    if (tid < off) red[tid] += red[tid + off];
    __syncthreads();
  }
  float lse = logf(red[0]);
  row[tid] = v - mx - lse;
}

extern "C" void kernel_launch(void* const* d_in, const int* in_sizes, int n_in,
                              void* d_out, int out_size, void* d_ws, size_t ws_size,
                              hipStream_t stream) {
  (void)in_sizes; (void)n_in; (void)out_size; (void)ws_size;
  const float* x = (const float*)d_in[0];
  const float* eWih = (const float*)d_in[1];
  const float* eWhh = (const float*)d_in[2];
  const float* ebih = (const float*)d_in[3];
  const float* ebhh = (const float*)d_in[4];
  const float* dWih = (const float*)d_in[5];
  const float* dWhh = (const float*)d_in[6];
  const float* dbih = (const float*)d_in[7];
  const float* dbhh = (const float*)d_in[8];
  const float* w1 = (const float*)d_in[9];
  const float* w2 = (const float*)d_in[10];
  const float* vt = (const float*)d_in[11];
  float* out = (float*)d_out;
  float* ws = (float*)d_ws;

  // workspace layout (floats) — total 31,522,816 floats = 126.1 MB
  float* E1 = ws;                    //  8,388,608  [S,B,W]
  float* H2 = E1 + 8388608ull;       //  8,388,608  [S,B,W]
  float* HBUF = H2 + 8388608ull;     //  8,388,608  [S,B,H] enc h's, then dec h's (alias)
  float* XPc = HBUF + 8388608ull;    //  4,194,304  [32 steps, B, 4H] chunked x-proj
  float* WTe = XPc + 4194304ull;     //  1,048,576  enc_Whh^T
  float* WTd = WTe + 1048576ull;     //  1,048,576  dec_Whh^T
  float* Cst = WTd + 1048576ull;     //     32,768  cell state
  float* Z = Cst + 32768ull;         //     32,768  zeros (h0)

  const int CH = 32;  // timesteps per x-projection chunk

  hipMemsetAsync(Cst, 0, 2 * 32768 * sizeof(float), stream);  // Cst + Z
  transpose_whh<<<dim3(16, 64), 256, 0, stream>>>(eWhh, WTe);
  transpose_whh<<<dim3(16, 64), 256, 0, stream>>>(dWhh, WTd);

  // ---- encoder: chunked x-projection + recurrent chain ----
  for (int c = 0; c < 256 / CH; ++c) {
    gemm_fp32<<<dim3(16, CH / 2), 256, 0, stream>>>(x, eWih, ebih, ebhh, XPc, 2048, 256,
                                                    1, c * CH * 64);
    for (int tl = 0; tl < CH; ++tl) {
      int t = c * CH + tl;
      const float* hp = t ? (HBUF + (size_t)(t - 1) * BH_) : Z;
      lstm_step<<<256, 256, 0, stream>>>(hp, Cst, Cst, XPc + (size_t)tl * 64 * 2048, WTe,
                                         HBUF + (size_t)t * BH_, 1);
    }
  }
  // e1 = enc_out @ w1.T   (must finish before decoder overwrites HBUF)
  gemm_fp32<<<dim3(4, 128), 256, 0, stream>>>(HBUF, w1, nullptr, nullptr, E1, 512, 512,
                                              0, 0);
  // ---- decoder: h chain only (cell pinned at cT); h0 = HBUF row 255 ----
  for (int c = 0; c < 256 / CH; ++c) {
    gemm_fp32<<<dim3(16, CH / 2), 256, 0, stream>>>(x, dWih, dbih, dbhh, XPc, 2048, 256,
                                                    1, c * CH * 64);
    for (int tl = 0; tl < CH; ++tl) {
      int t = c * CH + tl;
      const float* hp = t ? (HBUF + (size_t)(t - 1) * BH_) : (HBUF + 255ull * BH_);
      lstm_step<<<256, 256, 0, stream>>>(hp, Cst, nullptr, XPc + (size_t)tl * 64 * 2048,
                                         WTd, HBUF + (size_t)t * BH_, 0);
    }
  }
  // H2 = dec_h @ w2.T
  gemm_fp32<<<dim3(4, 128), 256, 0, stream>>>(HBUF, w2, nullptr, nullptr, H2, 512, 512,
                                              0, 0);
  scorer<<<dim3(32, 64), 128, 0, stream>>>(E1, H2, vt, out);
  logsoftmax_kernel<<<16384, 256, 0, stream>>>(out);
}